// Round 2
// baseline (255.480 us; speedup 1.0000x reference)
//
#include <hip/hip_runtime.h>

// Problem constants (fixed by setup_inputs):
//   img:  [B=4, C=1, D=64, H=192, W=192]  fp32
//   flow: [B=4, 3,   D=64, H=192, W=192]  fp32
//   out:  [B=4, C=1, D=64, H=192, W=192]  fp32
#define B_  4
#define D_  64
#define H_  192
#define W_  192
#define HW_ (H_ * W_)
#define DHW_ (D_ * H_ * W_)
#define NTOT (B_ * DHW_)
#define VEC 4                       // outputs per thread; W_ % VEC == 0 so a
                                    // 4-group never crosses a row boundary
#define NTHREADS (NTOT / VEC)

typedef float f4 __attribute__((ext_vector_type(4)));

__global__ __launch_bounds__(256) void warp3d_kernel(
    const float* __restrict__ img,
    const float* __restrict__ flow,
    float* __restrict__ out)
{
    int t = blockIdx.x * blockDim.x + threadIdx.x;
    if (t >= NTHREADS) return;

    int base = t * VEC;
    int b  = base / DHW_;
    int r  = base - b * DHW_;          // spatial index within volume
    int z  = r / HW_;
    int r2 = r - z * HW_;
    int y  = r2 / W_;
    int x  = r2 - y * W_;

    // flow is streamed once: nontemporal so it doesn't evict reused img lines
    const float* fl = flow + (size_t)b * 3 * DHW_ + r;
    f4 fx = __builtin_nontemporal_load((const f4*)(fl));
    f4 fy = __builtin_nontemporal_load((const f4*)(fl + DHW_));
    f4 fz = __builtin_nontemporal_load((const f4*)(fl + 2 * DHW_));

    const float* im = img + (size_t)b * DHW_;

    const float sx = (float)W_ / (float)(W_ - 1);
    const float sy = (float)H_ / (float)(H_ - 1);
    const float sz = (float)D_ / (float)(D_ - 1);

    // Stage 1: all addresses + weights (no loads yet)
    int  a000[VEC], a001[VEC], a010[VEC], a011[VEC];
    int  a100[VEC], a101[VEC], a110[VEC], a111[VEC];
    float wxv[VEC], wyv[VEC], wzv[VEC];

#pragma unroll
    for (int i = 0; i < VEC; ++i) {
        float ix = ((float)(x + i) + fx[i]) * sx - 0.5f;
        float iy = ((float)y + fy[i]) * sy - 0.5f;
        float iz = ((float)z + fz[i]) * sz - 0.5f;
        ix = fminf(fmaxf(ix, 0.0f), (float)(W_ - 1));
        iy = fminf(fmaxf(iy, 0.0f), (float)(H_ - 1));
        iz = fminf(fmaxf(iz, 0.0f), (float)(D_ - 1));

        float x0f = floorf(ix), y0f = floorf(iy), z0f = floorf(iz);
        wxv[i] = ix - x0f;
        wyv[i] = iy - y0f;
        wzv[i] = iz - z0f;

        int x0 = (int)x0f, y0 = (int)y0f, z0 = (int)z0f;
        int x1 = min(x0 + 1, W_ - 1);
        int y1 = min(y0 + 1, H_ - 1);
        int z1 = min(z0 + 1, D_ - 1);

        int bz0 = z0 * HW_, bz1 = z1 * HW_;
        int r00 = bz0 + y0 * W_;
        int r01 = bz0 + y1 * W_;
        int r10 = bz1 + y0 * W_;
        int r11 = bz1 + y1 * W_;
        a000[i] = r00 + x0;  a001[i] = r00 + x1;
        a010[i] = r01 + x0;  a011[i] = r01 + x1;
        a100[i] = r10 + x0;  a101[i] = r10 + x1;
        a110[i] = r11 + x0;  a111[i] = r11 + x1;
    }

    // Stage 2: issue all 32 gathers (independent -> deep MLP)
    float v000[VEC], v001[VEC], v010[VEC], v011[VEC];
    float v100[VEC], v101[VEC], v110[VEC], v111[VEC];
#pragma unroll
    for (int i = 0; i < VEC; ++i) {
        v000[i] = im[a000[i]];  v001[i] = im[a001[i]];
        v010[i] = im[a010[i]];  v011[i] = im[a011[i]];
        v100[i] = im[a100[i]];  v101[i] = im[a101[i]];
        v110[i] = im[a110[i]];  v111[i] = im[a111[i]];
    }

    // Stage 3: trilinear lerp + vector store
    f4 res;
#pragma unroll
    for (int i = 0; i < VEC; ++i) {
        float wx = wxv[i], wy = wyv[i], wz = wzv[i];
        float c00 = v000[i] + wx * (v001[i] - v000[i]);
        float c01 = v010[i] + wx * (v011[i] - v010[i]);
        float c10 = v100[i] + wx * (v101[i] - v100[i]);
        float c11 = v110[i] + wx * (v111[i] - v110[i]);
        float c0 = c00 + wy * (c01 - c00);
        float c1 = c10 + wy * (c11 - c10);
        res[i] = c0 + wz * (c1 - c0);
    }
    __builtin_nontemporal_store(res, (f4*)(out + base));
}

extern "C" void kernel_launch(void* const* d_in, const int* in_sizes, int n_in,
                              void* d_out, int out_size, void* d_ws, size_t ws_size,
                              hipStream_t stream) {
    const float* img  = (const float*)d_in[0];
    const float* flow = (const float*)d_in[1];
    float* out = (float*)d_out;

    const int threads = 256;
    const int blocks = (NTHREADS + threads - 1) / threads;
    warp3d_kernel<<<blocks, threads, 0, stream>>>(img, flow, out);
}

// Round 3
// 222.628 us; speedup vs baseline: 1.1476x; 1.1476x over previous
//
#include <hip/hip_runtime.h>

// Problem constants (fixed by setup_inputs):
//   img:  [B=4, C=1, D=64, H=192, W=192]  fp32
//   flow: [B=4, 3,   D=64, H=192, W=192]  fp32
//   out:  [B=4, C=1, D=64, H=192, W=192]  fp32
#define B_  4
#define D_  64
#define H_  192
#define W_  192
#define HW_ (H_ * W_)
#define DHW_ (D_ * H_ * W_)
#define NTOT (B_ * DHW_)
#define VEC 4                       // outputs per thread; W_ % VEC == 0 so a
                                    // 4-group never crosses a row boundary
#define NTHREADS (NTOT / VEC)

typedef float f4 __attribute__((ext_vector_type(4)));
typedef float f2 __attribute__((ext_vector_type(2)));
// 8B vector load at 4B alignment (gfx950 global loads support unaligned dword pairs)
typedef f2 f2u __attribute__((aligned(4)));

__global__ __launch_bounds__(256) void warp3d_kernel(
    const float* __restrict__ img,
    const float* __restrict__ flow,
    float* __restrict__ out)
{
    int t = blockIdx.x * blockDim.x + threadIdx.x;
    if (t >= NTHREADS) return;

    int base = t * VEC;
    int b  = base / DHW_;
    int r  = base - b * DHW_;          // spatial index within volume
    int z  = r / HW_;
    int r2 = r - z * HW_;
    int y  = r2 / W_;
    int x  = r2 - y * W_;

    // flow is streamed once: nontemporal so it doesn't evict reused img lines
    const float* fl = flow + (size_t)b * 3 * DHW_ + r;
    f4 fx = __builtin_nontemporal_load((const f4*)(fl));
    f4 fy = __builtin_nontemporal_load((const f4*)(fl + DHW_));
    f4 fz = __builtin_nontemporal_load((const f4*)(fl + 2 * DHW_));

    const float* im = img + (size_t)b * DHW_;

    const float sx = (float)W_ / (float)(W_ - 1);
    const float sy = (float)H_ / (float)(H_ - 1);
    const float sz = (float)D_ / (float)(D_ - 1);

    // Stage 1: all addresses + weights (no loads yet).
    // x-pair trick: one 8B load at xb = min(x0, W-2) covers (v000, v001):
    //   x0 <= W-2:  pair = (im[x0], im[x0+1]) -> v000=pair.x, v001=pair.y
    //   x0 == W-1:  pair = (im[W-2], im[W-1]) -> v000=pair.y, v001=pair.y
    //     (x1 = min(x0+1, W-1) = W-1 = pair.y)  -- exact in both cases
    int  a00[VEC], a01[VEC], a10[VEC], a11[VEC];   // pair base addresses
    int  hi0[VEC];                                  // x0 - xb (0 or 1)
    float wxv[VEC], wyv[VEC], wzv[VEC];

#pragma unroll
    for (int i = 0; i < VEC; ++i) {
        float ix = ((float)(x + i) + fx[i]) * sx - 0.5f;
        float iy = ((float)y + fy[i]) * sy - 0.5f;
        float iz = ((float)z + fz[i]) * sz - 0.5f;
        ix = fminf(fmaxf(ix, 0.0f), (float)(W_ - 1));
        iy = fminf(fmaxf(iy, 0.0f), (float)(H_ - 1));
        iz = fminf(fmaxf(iz, 0.0f), (float)(D_ - 1));

        float x0f = floorf(ix), y0f = floorf(iy), z0f = floorf(iz);
        wxv[i] = ix - x0f;
        wyv[i] = iy - y0f;
        wzv[i] = iz - z0f;

        int x0 = (int)x0f, y0 = (int)y0f, z0 = (int)z0f;
        int y1 = min(y0 + 1, H_ - 1);
        int z1 = min(z0 + 1, D_ - 1);
        int xb = min(x0, W_ - 2);
        hi0[i] = x0 - xb;               // 1 only when x0 == W-1

        int bz0 = z0 * HW_, bz1 = z1 * HW_;
        a00[i] = bz0 + y0 * W_ + xb;
        a01[i] = bz0 + y1 * W_ + xb;
        a10[i] = bz1 + y0 * W_ + xb;
        a11[i] = bz1 + y1 * W_ + xb;
    }

    // Stage 2: 4 pair-gathers per output (was 8 scalar gathers)
    f2 p00[VEC], p01[VEC], p10[VEC], p11[VEC];
#pragma unroll
    for (int i = 0; i < VEC; ++i) {
        p00[i] = *(const f2u*)(im + a00[i]);
        p01[i] = *(const f2u*)(im + a01[i]);
        p10[i] = *(const f2u*)(im + a10[i]);
        p11[i] = *(const f2u*)(im + a11[i]);
    }

    // Stage 3: trilinear lerp + vector store
    f4 res;
#pragma unroll
    for (int i = 0; i < VEC; ++i) {
        bool hi = (hi0[i] != 0);
        float v000 = hi ? p00[i].y : p00[i].x;
        float v010 = hi ? p01[i].y : p01[i].x;
        float v100 = hi ? p10[i].y : p10[i].x;
        float v110 = hi ? p11[i].y : p11[i].x;
        float v001 = p00[i].y;
        float v011 = p01[i].y;
        float v101 = p10[i].y;
        float v111 = p11[i].y;

        float wx = wxv[i], wy = wyv[i], wz = wzv[i];
        float c00 = v000 + wx * (v001 - v000);
        float c01 = v010 + wx * (v011 - v010);
        float c10 = v100 + wx * (v101 - v100);
        float c11 = v110 + wx * (v111 - v110);
        float c0 = c00 + wy * (c01 - c00);
        float c1 = c10 + wy * (c11 - c10);
        res[i] = c0 + wz * (c1 - c0);
    }
    __builtin_nontemporal_store(res, (f4*)(out + base));
}

extern "C" void kernel_launch(void* const* d_in, const int* in_sizes, int n_in,
                              void* d_out, int out_size, void* d_ws, size_t ws_size,
                              hipStream_t stream) {
    const float* img  = (const float*)d_in[0];
    const float* flow = (const float*)d_in[1];
    float* out = (float*)d_out;

    const int threads = 256;
    const int blocks = (NTHREADS + threads - 1) / threads;
    warp3d_kernel<<<blocks, threads, 0, stream>>>(img, flow, out);
}

// Round 4
// 216.000 us; speedup vs baseline: 1.1828x; 1.0307x over previous
//
#include <hip/hip_runtime.h>

// Problem constants (fixed by setup_inputs):
//   img:  [B=4, C=1, D=64, H=192, W=192]  fp32
//   flow: [B=4, 3,   D=64, H=192, W=192]  fp32
//   out:  [B=4, C=1, D=64, H=192, W=192]  fp32
#define B_  4
#define D_  64
#define H_  192
#define W_  192
#define HW_ (H_ * W_)
#define DHW_ (D_ * H_ * W_)
#define NTOT (B_ * DHW_)

// Tile: full-x rows, TY x TZ in y,z. Staged window adds +-4 halo in y and z
// (x is clamped to [0,191] and full rows are staged -> no x halo needed).
#define TY 8
#define TZ 2
#define SY (TY + 8)            // 16 staged rows
#define SZ (TZ + 8)            // 10 staged planes
#define SPLANE (SY * W_)       // 3072 floats per staged plane
#define SLDS (SZ * SPLANE)     // 30720 floats = 120 KB
#define TILE_OUT (W_ * TY * TZ)    // 3072 outputs per workgroup
#define VEC 4
#define TPB (TILE_OUT / VEC)       // 768 threads
#define NWG_Y (H_ / TY)        // 24
#define NWG_Z (D_ / TZ)        // 32
#define NWG (B_ * NWG_Z * NWG_Y)   // 3072 workgroups

typedef float f4 __attribute__((ext_vector_type(4)));
typedef float f2 __attribute__((ext_vector_type(2)));
typedef f2 f2u __attribute__((aligned(4)));

__global__ __launch_bounds__(TPB, 1) void warp3d_kernel(
    const float* __restrict__ img,
    const float* __restrict__ flow,
    float* __restrict__ out)
{
    __shared__ float lds[SLDS];    // 120 KB (gfx950: 160 KB/CU available)

    int wg = blockIdx.x;
    int b  = wg / (NWG_Z * NWG_Y);
    int rr = wg - b * (NWG_Z * NWG_Y);
    int tz = rr / NWG_Y;
    int Z  = tz * TZ;
    int Y  = (rr - tz * NWG_Y) * TY;
    // sliding staged window, clamped fully in-bounds
    int Zs = min(max(Z - 4, 0), D_ - SZ);
    int Ys = min(max(Y - 4, 0), H_ - SY);

    const float* im = img + (size_t)b * DHW_;
    int t = threadIdx.x;

    // ---- stage 192x16x10 window into LDS (one f4 per thread per plane) ----
    {
        int yy = (t * 4) / W_;             // 0..15
        int xs = (t * 4) - yy * W_;        // multiple of 4, no row crossing
        const float* src = im + (Ys + yy) * W_ + xs;
#pragma unroll
        for (int j = 0; j < SZ; ++j) {
            f4 v = *(const f4*)(src + (size_t)(Zs + j) * HW_);
            *(f4*)(lds + j * SPLANE + t * 4) = v;
        }
    }
    __syncthreads();

    // ---- this thread's 4 outputs ----
    int o  = t * VEC;
    int x  = o % W_;
    int q  = o / W_;                       // row id within tile, 0..15
    int yi = q % TY;
    int zi = q / TY;
    int y  = Y + yi;
    int z  = Z + zi;

    size_t nbase = (size_t)b * DHW_ + ((size_t)z * H_ + y) * W_ + x;
    const float* fl = flow + (size_t)b * 3 * DHW_ + ((size_t)z * H_ + y) * W_ + x;
    f4 fx = __builtin_nontemporal_load((const f4*)fl);
    f4 fy = __builtin_nontemporal_load((const f4*)(fl + DHW_));
    f4 fz = __builtin_nontemporal_load((const f4*)(fl + 2 * DHW_));

    const float sx = (float)W_ / (float)(W_ - 1);
    const float sy = (float)H_ / (float)(H_ - 1);
    const float sz = (float)D_ / (float)(D_ - 1);

    int   xb[VEC], y0a[VEC], z0a[VEC], hi[VEC], val[VEC];
    float wxv[VEC], wyv[VEC], wzv[VEC];

#pragma unroll
    for (int i = 0; i < VEC; ++i) {
        float ix = ((float)(x + i) + fx[i]) * sx - 0.5f;
        float iy = ((float)y + fy[i]) * sy - 0.5f;
        float iz = ((float)z + fz[i]) * sz - 0.5f;
        ix = fminf(fmaxf(ix, 0.0f), (float)(W_ - 1));
        iy = fminf(fmaxf(iy, 0.0f), (float)(H_ - 1));
        iz = fminf(fmaxf(iz, 0.0f), (float)(D_ - 1));

        float x0f = floorf(ix), y0f = floorf(iy), z0f = floorf(iz);
        wxv[i] = ix - x0f;
        wyv[i] = iy - y0f;
        wzv[i] = iz - z0f;

        int x0 = (int)x0f, y0 = (int)y0f, z0 = (int)z0f;
        int xbi = min(x0, W_ - 2);
        xb[i] = xbi;
        hi[i] = x0 - xbi;                  // 1 only when x0 == W-1
        y0a[i] = y0;
        z0a[i] = z0;
        int y1 = min(y0 + 1, H_ - 1);
        int z1 = min(z0 + 1, D_ - 1);
        val[i] = (y0 >= Ys) & (y1 <= Ys + SY - 1) &
                 (z0 >= Zs) & (z1 <= Zs + SZ - 1);
    }

    f4 res;
#pragma unroll
    for (int i = 0; i < VEC; ++i) {
        int y0 = y0a[i], z0 = z0a[i];
        int y1 = min(y0 + 1, H_ - 1);
        int z1 = min(z0 + 1, D_ - 1);
        float v000, v001, v010, v011, v100, v101, v110, v111;
        if (val[i]) {
            int i00 = ((z0 - Zs) * SY + (y0 - Ys)) * W_ + xb[i];
            int i01 = ((z0 - Zs) * SY + (y1 - Ys)) * W_ + xb[i];
            int i10 = ((z1 - Zs) * SY + (y0 - Ys)) * W_ + xb[i];
            int i11 = ((z1 - Zs) * SY + (y1 - Ys)) * W_ + xb[i];
            v000 = lds[i00]; v001 = lds[i00 + 1];
            v010 = lds[i01]; v011 = lds[i01 + 1];
            v100 = lds[i10]; v101 = lds[i10 + 1];
            v110 = lds[i11]; v111 = lds[i11 + 1];
        } else {
            // exact fallback (rare): same pair-load scheme as before, global
            f2 p00 = *(const f2u*)(im + (z0 * H_ + y0) * W_ + xb[i]);
            f2 p01 = *(const f2u*)(im + (z0 * H_ + y1) * W_ + xb[i]);
            f2 p10 = *(const f2u*)(im + (z1 * H_ + y0) * W_ + xb[i]);
            f2 p11 = *(const f2u*)(im + (z1 * H_ + y1) * W_ + xb[i]);
            v000 = p00.x; v001 = p00.y;
            v010 = p01.x; v011 = p01.y;
            v100 = p10.x; v101 = p10.y;
            v110 = p11.x; v111 = p11.y;
        }
        if (hi[i]) { v000 = v001; v010 = v011; v100 = v101; v110 = v111; }

        float wx = wxv[i], wy = wyv[i], wz = wzv[i];
        float c00 = v000 + wx * (v001 - v000);
        float c01 = v010 + wx * (v011 - v010);
        float c10 = v100 + wx * (v101 - v100);
        float c11 = v110 + wx * (v111 - v110);
        float c0 = c00 + wy * (c01 - c00);
        float c1 = c10 + wy * (c11 - c10);
        res[i] = c0 + wz * (c1 - c0);
    }
    __builtin_nontemporal_store(res, (f4*)(out + nbase));
}

extern "C" void kernel_launch(void* const* d_in, const int* in_sizes, int n_in,
                              void* d_out, int out_size, void* d_ws, size_t ws_size,
                              hipStream_t stream) {
    const float* img  = (const float*)d_in[0];
    const float* flow = (const float*)d_in[1];
    float* out = (float*)d_out;

    warp3d_kernel<<<NWG, TPB, 0, stream>>>(img, flow, out);
}